// Round 1
// 845.488 us; speedup vs baseline: 1.0581x; 1.0581x over previous
//
#include <hip/hip_runtime.h>
#include <cstdint>
#include <cstddef>

#define TOKENS 32768
#define DOUT 1024

typedef __attribute__((ext_vector_type(8))) short short8;
typedef __attribute__((ext_vector_type(4))) float f32x4;

__device__ __constant__ const int KS[4] = {1536, 1024, 512, 256};
// arena offsets in shorts
__device__ __constant__ const size_t OFFA[4] = {
    0, (size_t)TOKENS * 1536, (size_t)TOKENS * 2560, (size_t)TOKENS * 3072};
__device__ __constant__ const size_t OFFB[4] = {
    0, (size_t)DOUT * 1536, (size_t)DOUT * 2560, (size_t)DOUT * 3072};

#define GLDS16(g, l)                                                        \
    __builtin_amdgcn_global_load_lds(                                       \
        (const __attribute__((address_space(1))) void*)(g),                 \
        (__attribute__((address_space(3))) void*)(l), 16, 0, 0)

// fp32 -> bf16 bits, round-nearest-even (inputs are finite)
__device__ __forceinline__ short f2bf(float x) {
    unsigned u = __builtin_bit_cast(unsigned, x);
    u = (u + 0x7FFFu + ((u >> 16) & 1u)) >> 16;
    return (short)u;
}

// ---- kernel 1: bucket token positions by category --------------------------
__global__ void compact_kernel(const int* __restrict__ tok_ids,
                               const int* __restrict__ cat_table,
                               int* __restrict__ counts,
                               int* __restrict__ lists) {
    int i = blockIdx.x * 256 + threadIdx.x;
    int tok = tok_ids[i];
    int c = cat_table[tok];
    int pos = atomicAdd(&counts[c], 1);
    lists[c * TOKENS + pos] = (int)(((unsigned)tok << 15) | (unsigned)i);
}

// ---- kernel 2: W[K][1024] fp32 -> bf16 panel layout ------------------------
// Wt element (n, k) at OFFB[cat] + ((n>>7)*(K>>5) + (k>>5))*4096
//                              + ((k>>3)&3)*1024 + (n&127)*8 + (k&7)
__global__ __launch_bounds__(256) void conv_w_kernel(
    const float* __restrict__ W0, const float* __restrict__ W1,
    const float* __restrict__ W2, const float* __restrict__ W3,
    short* __restrict__ Wt_arena) {
    int p = blockIdx.x;  // flattened k-panel over cats: {48,32,16,8} -> 104
    int cat, panel;
    if (p < 48)      { cat = 0; panel = p; }
    else if (p < 80) { cat = 1; panel = p - 48; }
    else if (p < 96) { cat = 2; panel = p - 80; }
    else             { cat = 3; panel = p - 96; }
    const float* W = cat == 0 ? W0 : cat == 1 ? W1 : cat == 2 ? W2 : W3;
    const int K = KS[cat];
    const int nt = blockIdx.y;
    short* dst = Wt_arena + OFFB[cat] +
                 ((size_t)nt * (size_t)(K >> 5) + panel) * 4096;
    for (int ch = threadIdx.x; ch < 512; ch += 256) {
        int quad = ch >> 7, n = ch & 127;
        int kb = panel * 32 + quad * 8;
        const float* src = W + (size_t)kb * DOUT + nt * 128 + n;
        short8 s;
#pragma unroll
        for (int j = 0; j < 8; ++j) s[j] = f2bf(src[(size_t)j * DOUT]);
        *(short8*)(dst + quad * 1024 + n * 8) = s;
    }
}

// ---- kernel 3: gather emb rows -> compact bf16 A in panel layout -----------
// A element (row r, k) at OFFA[cat] + ((r>>7)*(K>>5) + (k>>5))*4096
//                              + ((k>>3)&3)*1024 + (r&127)*8 + (k&7)
__global__ __launch_bounds__(256) void gather_a_kernel(
    const float* __restrict__ e0, const float* __restrict__ e1,
    const float* __restrict__ e2, const float* __restrict__ e3,
    short* __restrict__ A_arena, const int* __restrict__ lists,
    const int* __restrict__ counts) {
    const int cat = blockIdx.y;
    const float* emb = cat == 0 ? e0 : cat == 1 ? e1 : cat == 2 ? e2 : e3;
    const int K = KS[cat];
    short* A = A_arena + OFFA[cat];
    const int count = counts[cat];
    const int w = threadIdx.x >> 6, L = threadIdx.x & 63;
    const int groups = (count + 3) >> 2;
    for (int g = blockIdx.x * 4 + w; g < groups; g += gridDim.x * 4) {
        int row = g * 4 + (L & 3);
        int tok = 0;
        if (row < count) tok = (int)(((unsigned)lists[cat * TOKENS + row]) >> 15);
        const float* src = emb + (size_t)tok * (size_t)K;
        short* dstrow = A + (size_t)(row >> 7) * (size_t)(K >> 5) * 4096 +
                        (row & 127) * 8;
        for (int k = (L >> 2) * 8; k < K; k += 128) {
            float4 f0 = *(const float4*)(src + k);
            float4 f1 = *(const float4*)(src + k + 4);
            short8 s;
            s[0] = f2bf(f0.x); s[1] = f2bf(f0.y);
            s[2] = f2bf(f0.z); s[3] = f2bf(f0.w);
            s[4] = f2bf(f1.x); s[5] = f2bf(f1.y);
            s[6] = f2bf(f1.z); s[7] = f2bf(f1.w);
            *(short8*)(dstrow + (size_t)(k >> 5) * 4096 + ((k >> 3) & 3) * 1024) = s;
        }
    }
}

// ---- kernel 4: fused all-category GEMM -------------------------------------
// out[dst, n] = A_c[row, :] @ W_c[:, n] + b_c[n]
// Grid: 1D, 2112 blocks. Decode so that id%8 == mt%8: all 8 nt-blocks of one
// m-tile land on the SAME XCD (round-robin id%8 -> XCD), back-to-back in time,
// so each 384KB A-panel is fetched from HBM once and L2-served 8x.
__global__ __launch_bounds__(256) void gemm_fused_kernel(
    const short* __restrict__ A_arena, const short* __restrict__ Wt_arena,
    const float* __restrict__ b0, const float* __restrict__ b1,
    const float* __restrict__ b2, const float* __restrict__ b3,
    const int* __restrict__ lists, const int* __restrict__ counts,
    float* __restrict__ out) {
    __shared__ short lds_A[2][4096];  // double-buffered [quad][128 rows][8]
    __shared__ short lds_B[2][4096];
    __shared__ int row_dst[128];

    const int c0 = counts[0], c1 = counts[1], c2 = counts[2], c3 = counts[3];
    const int t0 = (c0 + 127) >> 7, t1 = (c1 + 127) >> 7;
    const int t2 = (c2 + 127) >> 7, t3 = (c3 + 127) >> 7;
    const int mt_total = t0 + t1 + t2 + t3;

    const int id = blockIdx.x;
    const int mt_flat = ((id >> 6) << 3) + (id & 7);  // chunk*8 + id%8
    const int nt = (id >> 3) & 7;
    if (mt_flat >= mt_total) return;

    int cat, mt, count;
    if (mt_flat < t0)                { cat = 0; mt = mt_flat; count = c0; }
    else if (mt_flat < t0 + t1)      { cat = 1; mt = mt_flat - t0; count = c1; }
    else if (mt_flat < t0 + t1 + t2) { cat = 2; mt = mt_flat - t0 - t1; count = c2; }
    else                             { cat = 3; mt = mt_flat - t0 - t1 - t2; count = c3; }

    const int K = KS[cat];
    const int kp_n = K >> 5;
    const short* Abase = A_arena + OFFA[cat] + (size_t)mt * kp_n * 4096;
    const short* Bbase = Wt_arena + OFFB[cat] + (size_t)nt * kp_n * 4096;
    const float* bias = cat == 0 ? b0 : cat == 1 ? b1 : cat == 2 ? b2 : b3;
    const int m0 = mt << 7;
    const int valid = min(128, count - m0);

    const int t = threadIdx.x;
    if (t < 128)
        row_dst[t] = (t < valid) ? (lists[cat * TOKENS + m0 + t] & 32767) : -1;

    const int w = t >> 6, L = t & 63;
    const int quad = L >> 4, l16 = L & 15;
    const int m_off = (w & 1) * 64;
    const int n_off = (w >> 1) * 64;
    const int s0 = (w * 2) * 64 + L;      // slot for issue 0
    const int s1 = (w * 2 + 1) * 64 + L;  // slot for issue 1

    f32x4 acc[4][4];
#pragma unroll
    for (int i = 0; i < 4; ++i)
#pragma unroll
        for (int j = 0; j < 4; ++j) acc[i][j] = (f32x4)0.0f;

#define STAGE(buf, kp)                                                      \
    do {                                                                    \
        const short* gA_ = Abase + (size_t)(kp) * 4096;                     \
        const short* gB_ = Bbase + (size_t)(kp) * 4096;                     \
        GLDS16(gA_ + (size_t)s0 * 8, &lds_A[buf][(w * 2) * 512]);           \
        GLDS16(gA_ + (size_t)s1 * 8, &lds_A[buf][(w * 2 + 1) * 512]);       \
        GLDS16(gB_ + (size_t)s0 * 8, &lds_B[buf][(w * 2) * 512]);           \
        GLDS16(gB_ + (size_t)s1 * 8, &lds_B[buf][(w * 2 + 1) * 512]);       \
    } while (0)

#define COMPUTE(buf)                                                        \
    do {                                                                    \
        short8 af[4], bf[4];                                                \
        _Pragma("unroll") for (int mi = 0; mi < 4; ++mi)                    \
            af[mi] = *(const short8*)&lds_A[buf][quad * 1024 +              \
                                                 (m_off + mi * 16 + l16) * 8]; \
        _Pragma("unroll") for (int ni = 0; ni < 4; ++ni)                    \
            bf[ni] = *(const short8*)&lds_B[buf][quad * 1024 +              \
                                                 (n_off + ni * 16 + l16) * 8]; \
        _Pragma("unroll") for (int mi = 0; mi < 4; ++mi)                    \
            _Pragma("unroll") for (int ni = 0; ni < 4; ++ni)                \
                acc[mi][ni] = __builtin_amdgcn_mfma_f32_16x16x32_bf16(      \
                    af[mi], bf[ni], acc[mi][ni], 0, 0, 0);                  \
    } while (0)

    // Pipelined K-loop (T3-min): stage next panel into the alternate buffer
    // BEFORE computing the current one. __syncthreads' implicit
    // s_waitcnt vmcnt(0) then drains loads issued ~one compute-phase earlier
    // (L2-latency thanks to the XCD chunking) instead of stalling cold.
    STAGE(0, 0);
    __syncthreads();  // row_dst + buf0 visible
    int cur = 0;
    for (int kp = 0; kp < kp_n - 1; ++kp) {
        STAGE(cur ^ 1, kp + 1);
        COMPUTE(cur);
        __syncthreads();
        cur ^= 1;
    }
    COMPUTE(cur);

#undef STAGE
#undef COMPUTE

    float bv[4];
#pragma unroll
    for (int ni = 0; ni < 4; ++ni)
        bv[ni] = bias[nt * 128 + n_off + ni * 16 + l16];

#pragma unroll
    for (int mi = 0; mi < 4; ++mi) {
        int mb = m_off + mi * 16 + quad * 4;
#pragma unroll
        for (int r = 0; r < 4; ++r) {
            int m = mb + r;
            if (m < valid) {
                size_t dst = (size_t)row_dst[m] * DOUT;
#pragma unroll
                for (int ni = 0; ni < 4; ++ni)
                    out[dst + nt * 128 + n_off + ni * 16 + l16] =
                        acc[mi][ni][r] + bv[ni];
            }
        }
    }
}

// ---- fallback GEMM (round-1, known-good; used only if ws too small) --------
__global__ __launch_bounds__(256) void gemm_direct_kernel(
    const float* __restrict__ emb, const float* __restrict__ W,
    const float* __restrict__ bias, const int* __restrict__ list,
    const int* __restrict__ count_p, float* __restrict__ out, int K) {
    __shared__ short lds_A[128 * 40];
    __shared__ short lds_B[128 * 40];
    __shared__ int row_tok[128];
    __shared__ int row_dst[128];

    const int count = *count_p;
    const int m0 = blockIdx.x * 128;
    if (m0 >= count) return;
    const int valid = min(128, count - m0);
    const int n0 = blockIdx.y * 128;
    const int t = threadIdx.x;
    if (t < 128) {
        if (t < valid) {
            unsigned pack = (unsigned)list[m0 + t];
            row_tok[t] = (int)(pack >> 15);
            row_dst[t] = (int)(pack & 32767u);
        } else { row_tok[t] = 0; row_dst[t] = -1; }
    }
    __syncthreads();

    const int w = t >> 6, L = t & 63;
    const int quad = L >> 4, l16 = L & 15;
    const int m_off = (w & 1) * 64, n_off = (w >> 1) * 64;
    f32x4 acc[4][4];
#pragma unroll
    for (int i = 0; i < 4; ++i)
#pragma unroll
        for (int j = 0; j < 4; ++j) acc[i][j] = (f32x4)0.0f;

    const int ar = t >> 1, acg = (t & 1) * 16;
    const size_t arow = (size_t)row_tok[ar] * (size_t)K;

    for (int k0 = 0; k0 < K; k0 += 32) {
        const float4* src = reinterpret_cast<const float4*>(emb + arow + k0 + acg);
        float4 f0 = src[0], f1 = src[1], f2 = src[2], f3 = src[3];
        short8 v0, v1;
        v0[0] = f2bf(f0.x); v0[1] = f2bf(f0.y); v0[2] = f2bf(f0.z); v0[3] = f2bf(f0.w);
        v0[4] = f2bf(f1.x); v0[5] = f2bf(f1.y); v0[6] = f2bf(f1.z); v0[7] = f2bf(f1.w);
        v1[0] = f2bf(f2.x); v1[1] = f2bf(f2.y); v1[2] = f2bf(f2.z); v1[3] = f2bf(f2.w);
        v1[4] = f2bf(f3.x); v1[5] = f2bf(f3.y); v1[6] = f2bf(f3.z); v1[7] = f2bf(f3.w);
        *(short8*)&lds_A[ar * 40 + acg] = v0;
        *(short8*)&lds_A[ar * 40 + acg + 8] = v1;
        const int bk = t >> 3, bq = (t & 7) * 4;
#pragma unroll
        for (int q = 0; q < 4; ++q) {
            int nb = bq + q * 32;
            float4 f = *reinterpret_cast<const float4*>(
                W + (size_t)(k0 + bk) * DOUT + n0 + nb);
            lds_B[(nb + 0) * 40 + bk] = f2bf(f.x);
            lds_B[(nb + 1) * 40 + bk] = f2bf(f.y);
            lds_B[(nb + 2) * 40 + bk] = f2bf(f.z);
            lds_B[(nb + 3) * 40 + bk] = f2bf(f.w);
        }
        __syncthreads();
        short8 af[4], bf[4];
#pragma unroll
        for (int mi = 0; mi < 4; ++mi)
            af[mi] = *(const short8*)&lds_A[(m_off + mi * 16 + l16) * 40 + quad * 8];
#pragma unroll
        for (int ni = 0; ni < 4; ++ni)
            bf[ni] = *(const short8*)&lds_B[(n_off + ni * 16 + l16) * 40 + quad * 8];
#pragma unroll
        for (int mi = 0; mi < 4; ++mi)
#pragma unroll
            for (int ni = 0; ni < 4; ++ni)
                acc[mi][ni] = __builtin_amdgcn_mfma_f32_16x16x32_bf16(
                    af[mi], bf[ni], acc[mi][ni], 0, 0, 0);
        __syncthreads();
    }
    float bv[4];
#pragma unroll
    for (int ni = 0; ni < 4; ++ni) bv[ni] = bias[n0 + n_off + ni * 16 + l16];
#pragma unroll
    for (int mi = 0; mi < 4; ++mi) {
        int mb = m_off + mi * 16 + quad * 4;
#pragma unroll
        for (int r = 0; r < 4; ++r) {
            int m = mb + r;
            if (m < valid) {
                size_t dst = (size_t)row_dst[m] * DOUT;
#pragma unroll
                for (int ni = 0; ni < 4; ++ni)
                    out[dst + n0 + n_off + ni * 16 + l16] = acc[mi][ni][r] + bv[ni];
            }
        }
    }
}

// ---------------------------------------------------------------------------
extern "C" void kernel_launch(void* const* d_in, const int* in_sizes, int n_in,
                              void* d_out, int out_size, void* d_ws, size_t ws_size,
                              hipStream_t stream) {
    const int* token_ids = (const int*)d_in[0];
    const int* cat_table = (const int*)d_in[1];
    const float* emb[4] = {(const float*)d_in[2], (const float*)d_in[5],
                           (const float*)d_in[8], (const float*)d_in[11]};
    const float* Wm[4]  = {(const float*)d_in[3], (const float*)d_in[6],
                           (const float*)d_in[9], (const float*)d_in[12]};
    const float* bm[4]  = {(const float*)d_in[4], (const float*)d_in[7],
                           (const float*)d_in[10], (const float*)d_in[13]};
    float* out = (float*)d_out;

    char* ws = (char*)d_ws;
    int* counts = (int*)ws;                        // 16 B
    int* lists = (int*)(ws + 16);                  // 4*32768*4 = 512 KB
    size_t off = (16 + (size_t)4 * TOKENS * 4 + 255) & ~(size_t)255;
    short* wt_arena = (short*)(ws + off);          // 1024*3328*2 = 6.8 MB
    off += (size_t)DOUT * 3328 * sizeof(short);
    off = (off + 255) & ~(size_t)255;
    short* a_arena = (short*)(ws + off);           // 32768*3328*2 = 218 MB
    off += (size_t)TOKENS * 3328 * sizeof(short);
    const bool fast = (ws_size >= off);

    hipMemsetAsync(counts, 0, 16, stream);
    compact_kernel<<<TOKENS / 256, 256, 0, stream>>>(token_ids, cat_table,
                                                     counts, lists);
    if (fast) {
        conv_w_kernel<<<dim3(104, 8), 256, 0, stream>>>(
            Wm[0], Wm[1], Wm[2], Wm[3], wt_arena);
        gather_a_kernel<<<dim3(128, 4), 256, 0, stream>>>(
            emb[0], emb[1], emb[2], emb[3], a_arena, lists, counts);
        // 33 chunks * 64 = 2112 blocks covers mt_total <= 260 with 8 nt each
        gemm_fused_kernel<<<2112, 256, 0, stream>>>(
            a_arena, wt_arena, bm[0], bm[1], bm[2], bm[3], lists, counts, out);
    } else {
        dim3 grid(TOKENS / 128, DOUT / 128);
        for (int c = 0; c < 4; ++c) {
            const int Ks[4] = {1536, 1024, 512, 256};
            gemm_direct_kernel<<<grid, 256, 0, stream>>>(
                emb[c], Wm[c], bm[c], lists + c * TOKENS, counts + c, out, Ks[c]);
        }
    }
}

// Round 3
// 706.417 us; speedup vs baseline: 1.2664x; 1.1969x over previous
//
#include <hip/hip_runtime.h>
#include <cstdint>
#include <cstddef>

#define TOKENS 32768
#define DOUT 1024

typedef __attribute__((ext_vector_type(8))) short short8;
typedef __attribute__((ext_vector_type(4))) float f32x4;

__device__ __constant__ const int KS[4] = {1536, 1024, 512, 256};
// arena offsets in shorts
__device__ __constant__ const size_t OFFA[4] = {
    0, (size_t)TOKENS * 1536, (size_t)TOKENS * 2560, (size_t)TOKENS * 3072};
__device__ __constant__ const size_t OFFB[4] = {
    0, (size_t)DOUT * 1536, (size_t)DOUT * 2560, (size_t)DOUT * 3072};

#define GLDS16(g, l)                                                        \
    __builtin_amdgcn_global_load_lds(                                       \
        (const __attribute__((address_space(1))) void*)(g),                 \
        (__attribute__((address_space(3))) void*)(l), 16, 0, 0)

// fp32 -> bf16 bits, round-nearest-even (inputs are finite)
__device__ __forceinline__ short f2bf(float x) {
    unsigned u = __builtin_bit_cast(unsigned, x);
    u = (u + 0x7FFFu + ((u >> 16) & 1u)) >> 16;
    return (short)u;
}

// ---- kernel 1: bucket token positions by category --------------------------
// Wave-aggregated: one atomicAdd per wave per category (<=2048 total) instead
// of 32768 same-address fetch-adds (which serialize at the cache atomic unit).
__global__ void compact_kernel(const int* __restrict__ tok_ids,
                               const int* __restrict__ cat_table,
                               int* __restrict__ counts,
                               int* __restrict__ lists) {
    int i = blockIdx.x * 256 + threadIdx.x;
    int tok = tok_ids[i];
    int c = cat_table[tok];
    int lane = threadIdx.x & 63;
    unsigned long long lanes_below = (1ull << lane) - 1ull;
    int pos = 0;
#pragma unroll
    for (int cc = 0; cc < 4; ++cc) {
        unsigned long long m = __ballot(c == cc);
        if (c == cc) {
            int rank = __popcll(m & lanes_below);
            int base = 0;
            if (rank == 0) base = atomicAdd(&counts[cc], __popcll(m));
            base = __builtin_amdgcn_readfirstlane(base);  // rank-0 lane is first active
            pos = base + rank;
        }
    }
    lists[c * TOKENS + pos] = (int)(((unsigned)tok << 15) | (unsigned)i);
}

// ---- kernel 2: W[K][1024] fp32 -> bf16 panel layout ------------------------
// Wt element (n, k) at OFFB[cat] + ((n>>7)*(K>>5) + (k>>5))*4096
//                              + ((k>>3)&3)*1024 + (n&127)*8 + (k&7)
__global__ __launch_bounds__(256) void conv_w_kernel(
    const float* __restrict__ W0, const float* __restrict__ W1,
    const float* __restrict__ W2, const float* __restrict__ W3,
    short* __restrict__ Wt_arena) {
    int p = blockIdx.x;  // flattened k-panel over cats: {48,32,16,8} -> 104
    int cat, panel;
    if (p < 48)      { cat = 0; panel = p; }
    else if (p < 80) { cat = 1; panel = p - 48; }
    else if (p < 96) { cat = 2; panel = p - 80; }
    else             { cat = 3; panel = p - 96; }
    const float* W = cat == 0 ? W0 : cat == 1 ? W1 : cat == 2 ? W2 : W3;
    const int K = KS[cat];
    const int nt = blockIdx.y;
    short* dst = Wt_arena + OFFB[cat] +
                 ((size_t)nt * (size_t)(K >> 5) + panel) * 4096;
    for (int ch = threadIdx.x; ch < 512; ch += 256) {
        int quad = ch >> 7, n = ch & 127;
        int kb = panel * 32 + quad * 8;
        const float* src = W + (size_t)kb * DOUT + nt * 128 + n;
        short8 s;
#pragma unroll
        for (int j = 0; j < 8; ++j) s[j] = f2bf(src[(size_t)j * DOUT]);
        *(short8*)(dst + quad * 1024 + n * 8) = s;
    }
}

// ---- kernel 3: gather emb rows -> compact bf16 A in panel layout -----------
// A element (row r, k) at ((r>>7)*(K>>5) + (k>>5))*4096
//                        + ((k>>3)&3)*1024 + (r&127)*8 + (k&7)
// Compile-time K -> fully unrolled k-loop -> 2*(K/128) loads in flight.
template <int K>
__device__ __forceinline__ void gather_cat(
    const float* __restrict__ emb, short* __restrict__ A,
    const int* __restrict__ list, int count, int gstart, int gstep) {
    const int w = threadIdx.x >> 6, L = threadIdx.x & 63;
    const int groups = (count + 3) >> 2;
    for (int g = gstart + w; g < groups; g += gstep) {
        int row = g * 4 + (L & 3);
        if (row >= count) continue;  // guard: no store past the valid rows
        int tok = (int)(((unsigned)list[row]) >> 15);
        const float* src = emb + (size_t)tok * (size_t)K;
        short* dstrow = A + (size_t)(row >> 7) * (size_t)(K >> 5) * 4096 +
                        (row & 127) * 8;
#pragma unroll
        for (int kk = 0; kk < K / 128; ++kk) {
            int k = (L >> 2) * 8 + kk * 128;
            float4 f0 = *(const float4*)(src + k);
            float4 f1 = *(const float4*)(src + k + 4);
            short8 s;
            s[0] = f2bf(f0.x); s[1] = f2bf(f0.y);
            s[2] = f2bf(f0.z); s[3] = f2bf(f0.w);
            s[4] = f2bf(f1.x); s[5] = f2bf(f1.y);
            s[6] = f2bf(f1.z); s[7] = f2bf(f1.w);
            *(short8*)(dstrow + (size_t)(k >> 5) * 4096 + ((k >> 3) & 3) * 1024) = s;
        }
    }
}

__global__ __launch_bounds__(256) void gather_a_kernel(
    const float* __restrict__ e0, const float* __restrict__ e1,
    const float* __restrict__ e2, const float* __restrict__ e3,
    short* __restrict__ A_arena, const int* __restrict__ lists,
    const int* __restrict__ counts) {
    const int gstart = blockIdx.x * 4;
    const int gstep = gridDim.x * 4;
    switch (blockIdx.y) {
    case 0: gather_cat<1536>(e0, A_arena + OFFA[0], lists + 0 * TOKENS,
                             counts[0], gstart, gstep); break;
    case 1: gather_cat<1024>(e1, A_arena + OFFA[1], lists + 1 * TOKENS,
                             counts[1], gstart, gstep); break;
    case 2: gather_cat<512>(e2, A_arena + OFFA[2], lists + 2 * TOKENS,
                            counts[2], gstart, gstep); break;
    default: gather_cat<256>(e3, A_arena + OFFA[3], lists + 3 * TOKENS,
                             counts[3], gstart, gstep); break;
    }
}

// ---- kernel 4: fused all-category GEMM -------------------------------------
// out[dst, n] = A_c[row, :] @ W_c[:, n] + b_c[n]
// Grid: 1D, 2112 blocks. Decode so that id%8 == mt%8: all 8 nt-blocks of one
// m-tile land on the SAME XCD (round-robin id%8 -> XCD), back-to-back in time,
// so each 384KB A-panel is fetched from HBM once and L2-served 8x.
// K-loop: unrolled by 2 with COMPILE-TIME buffer indices so the backend can
// prove the in-flight global_load_lds (buf^1) don't alias the ds_reads (buf)
// and genuinely overlap them (runtime `cur` forces a vmcnt(0) drain).
__global__ __launch_bounds__(256) void gemm_fused_kernel(
    const short* __restrict__ A_arena, const short* __restrict__ Wt_arena,
    const float* __restrict__ b0, const float* __restrict__ b1,
    const float* __restrict__ b2, const float* __restrict__ b3,
    const int* __restrict__ lists, const int* __restrict__ counts,
    float* __restrict__ out) {
    __shared__ short lds_A[2][4096];  // double-buffered [quad][128 rows][8]
    __shared__ short lds_B[2][4096];
    __shared__ int row_dst[128];

    const int c0 = counts[0], c1 = counts[1], c2 = counts[2], c3 = counts[3];
    const int t0 = (c0 + 127) >> 7, t1 = (c1 + 127) >> 7;
    const int t2 = (c2 + 127) >> 7, t3 = (c3 + 127) >> 7;
    const int mt_total = t0 + t1 + t2 + t3;

    const int id = blockIdx.x;
    const int mt_flat = ((id >> 6) << 3) + (id & 7);  // chunk*8 + id%8
    const int nt = (id >> 3) & 7;
    if (mt_flat >= mt_total) return;

    int cat, mt, count;
    if (mt_flat < t0)                { cat = 0; mt = mt_flat; count = c0; }
    else if (mt_flat < t0 + t1)      { cat = 1; mt = mt_flat - t0; count = c1; }
    else if (mt_flat < t0 + t1 + t2) { cat = 2; mt = mt_flat - t0 - t1; count = c2; }
    else                             { cat = 3; mt = mt_flat - t0 - t1 - t2; count = c3; }

    const int K = KS[cat];
    const int kp_n = K >> 5;  // {48,32,16,8} -- always even
    const short* Abase = A_arena + OFFA[cat] + (size_t)mt * kp_n * 4096;
    const short* Bbase = Wt_arena + OFFB[cat] + (size_t)nt * kp_n * 4096;
    const float* bias = cat == 0 ? b0 : cat == 1 ? b1 : cat == 2 ? b2 : b3;
    const int m0 = mt << 7;
    const int valid = min(128, count - m0);

    const int t = threadIdx.x;
    if (t < 128)
        row_dst[t] = (t < valid) ? (lists[cat * TOKENS + m0 + t] & 32767) : -1;

    const int w = t >> 6, L = t & 63;
    const int quad = L >> 4, l16 = L & 15;
    const int m_off = (w & 1) * 64;
    const int n_off = (w >> 1) * 64;
    const int s0 = (w * 2) * 64 + L;      // slot for issue 0
    const int s1 = (w * 2 + 1) * 64 + L;  // slot for issue 1

    f32x4 acc[4][4];
#pragma unroll
    for (int i = 0; i < 4; ++i)
#pragma unroll
        for (int j = 0; j < 4; ++j) acc[i][j] = (f32x4)0.0f;

#define STAGE(buf, kp)                                                      \
    do {                                                                    \
        const short* gA_ = Abase + (size_t)(kp) * 4096;                     \
        const short* gB_ = Bbase + (size_t)(kp) * 4096;                     \
        GLDS16(gA_ + (size_t)s0 * 8, &lds_A[buf][(w * 2) * 512]);           \
        GLDS16(gA_ + (size_t)s1 * 8, &lds_A[buf][(w * 2 + 1) * 512]);       \
        GLDS16(gB_ + (size_t)s0 * 8, &lds_B[buf][(w * 2) * 512]);           \
        GLDS16(gB_ + (size_t)s1 * 8, &lds_B[buf][(w * 2 + 1) * 512]);       \
    } while (0)

#define COMPUTE(buf)                                                        \
    do {                                                                    \
        short8 af[4], bf[4];                                                \
        _Pragma("unroll") for (int mi = 0; mi < 4; ++mi)                    \
            af[mi] = *(const short8*)&lds_A[buf][quad * 1024 +              \
                                                 (m_off + mi * 16 + l16) * 8]; \
        _Pragma("unroll") for (int ni = 0; ni < 4; ++ni)                    \
            bf[ni] = *(const short8*)&lds_B[buf][quad * 1024 +              \
                                                 (n_off + ni * 16 + l16) * 8]; \
        _Pragma("unroll") for (int mi = 0; mi < 4; ++mi)                    \
            _Pragma("unroll") for (int ni = 0; ni < 4; ++ni)                \
                acc[mi][ni] = __builtin_amdgcn_mfma_f32_16x16x32_bf16(      \
                    af[mi], bf[ni], acc[mi][ni], 0, 0, 0);                  \
    } while (0)

    // Invariant at loop entry: buf0 holds panel kp.
    STAGE(0, 0);
    __syncthreads();  // row_dst + buf0 visible
    int kp = 0;
    for (; kp < kp_n - 2; kp += 2) {
        STAGE(1, kp + 1);   // in flight during COMPUTE(0)
        COMPUTE(0);
        __syncthreads();    // drains stage loads (issued ~1 compute earlier)
        STAGE(0, kp + 2);
        COMPUTE(1);
        __syncthreads();
    }
    STAGE(1, kp_n - 1);
    COMPUTE(0);
    __syncthreads();
    COMPUTE(1);

#undef STAGE
#undef COMPUTE

    float bv[4];
#pragma unroll
    for (int ni = 0; ni < 4; ++ni)
        bv[ni] = bias[nt * 128 + n_off + ni * 16 + l16];

#pragma unroll
    for (int mi = 0; mi < 4; ++mi) {
        int mb = m_off + mi * 16 + quad * 4;
#pragma unroll
        for (int r = 0; r < 4; ++r) {
            int m = mb + r;
            if (m < valid) {
                size_t dst = (size_t)row_dst[m] * DOUT;
#pragma unroll
                for (int ni = 0; ni < 4; ++ni)
                    out[dst + nt * 128 + n_off + ni * 16 + l16] =
                        acc[mi][ni][r] + bv[ni];
            }
        }
    }
}

// ---- fallback GEMM (round-1, known-good; used only if ws too small) --------
__global__ __launch_bounds__(256) void gemm_direct_kernel(
    const float* __restrict__ emb, const float* __restrict__ W,
    const float* __restrict__ bias, const int* __restrict__ list,
    const int* __restrict__ count_p, float* __restrict__ out, int K) {
    __shared__ short lds_A[128 * 40];
    __shared__ short lds_B[128 * 40];
    __shared__ int row_tok[128];
    __shared__ int row_dst[128];

    const int count = *count_p;
    const int m0 = blockIdx.x * 128;
    if (m0 >= count) return;
    const int valid = min(128, count - m0);
    const int n0 = blockIdx.y * 128;
    const int t = threadIdx.x;
    if (t < 128) {
        if (t < valid) {
            unsigned pack = (unsigned)list[m0 + t];
            row_tok[t] = (int)(pack >> 15);
            row_dst[t] = (int)(pack & 32767u);
        } else { row_tok[t] = 0; row_dst[t] = -1; }
    }
    __syncthreads();

    const int w = t >> 6, L = t & 63;
    const int quad = L >> 4, l16 = L & 15;
    const int m_off = (w & 1) * 64, n_off = (w >> 1) * 64;
    f32x4 acc[4][4];
#pragma unroll
    for (int i = 0; i < 4; ++i)
#pragma unroll
        for (int j = 0; j < 4; ++j) acc[i][j] = (f32x4)0.0f;

    const int ar = t >> 1, acg = (t & 1) * 16;
    const size_t arow = (size_t)row_tok[ar] * (size_t)K;

    for (int k0 = 0; k0 < K; k0 += 32) {
        const float4* src = reinterpret_cast<const float4*>(emb + arow + k0 + acg);
        float4 f0 = src[0], f1 = src[1], f2 = src[2], f3 = src[3];
        short8 v0, v1;
        v0[0] = f2bf(f0.x); v0[1] = f2bf(f0.y); v0[2] = f2bf(f0.z); v0[3] = f2bf(f0.w);
        v0[4] = f2bf(f1.x); v0[5] = f2bf(f1.y); v0[6] = f2bf(f1.z); v0[7] = f2bf(f1.w);
        v1[0] = f2bf(f2.x); v1[1] = f2bf(f2.y); v1[2] = f2bf(f2.z); v1[3] = f2bf(f2.w);
        v1[4] = f2bf(f3.x); v1[5] = f2bf(f3.y); v1[6] = f2bf(f3.z); v1[7] = f2bf(f3.w);
        *(short8*)&lds_A[ar * 40 + acg] = v0;
        *(short8*)&lds_A[ar * 40 + acg + 8] = v1;
        const int bk = t >> 3, bq = (t & 7) * 4;
#pragma unroll
        for (int q = 0; q < 4; ++q) {
            int nb = bq + q * 32;
            float4 f = *reinterpret_cast<const float4*>(
                W + (size_t)(k0 + bk) * DOUT + n0 + nb);
            lds_B[(nb + 0) * 40 + bk] = f2bf(f.x);
            lds_B[(nb + 1) * 40 + bk] = f2bf(f.y);
            lds_B[(nb + 2) * 40 + bk] = f2bf(f.z);
            lds_B[(nb + 3) * 40 + bk] = f2bf(f.w);
        }
        __syncthreads();
        short8 af[4], bf[4];
#pragma unroll
        for (int mi = 0; mi < 4; ++mi)
            af[mi] = *(const short8*)&lds_A[(m_off + mi * 16 + l16) * 40 + quad * 8];
#pragma unroll
        for (int ni = 0; ni < 4; ++ni)
            bf[ni] = *(const short8*)&lds_B[(n_off + ni * 16 + l16) * 40 + quad * 8];
#pragma unroll
        for (int mi = 0; mi < 4; ++mi)
#pragma unroll
            for (int ni = 0; ni < 4; ++ni)
                acc[mi][ni] = __builtin_amdgcn_mfma_f32_16x16x32_bf16(
                    af[mi], bf[ni], acc[mi][ni], 0, 0, 0);
        __syncthreads();
    }
    float bv[4];
#pragma unroll
    for (int ni = 0; ni < 4; ++ni) bv[ni] = bias[n0 + n_off + ni * 16 + l16];
#pragma unroll
    for (int mi = 0; mi < 4; ++mi) {
        int mb = m_off + mi * 16 + quad * 4;
#pragma unroll
        for (int r = 0; r < 4; ++r) {
            int m = mb + r;
            if (m < valid) {
                size_t dst = (size_t)row_dst[m] * DOUT;
#pragma unroll
                for (int ni = 0; ni < 4; ++ni)
                    out[dst + n0 + n_off + ni * 16 + l16] = acc[mi][ni][r] + bv[ni];
            }
        }
    }
}

// ---------------------------------------------------------------------------
extern "C" void kernel_launch(void* const* d_in, const int* in_sizes, int n_in,
                              void* d_out, int out_size, void* d_ws, size_t ws_size,
                              hipStream_t stream) {
    const int* token_ids = (const int*)d_in[0];
    const int* cat_table = (const int*)d_in[1];
    const float* emb[4] = {(const float*)d_in[2], (const float*)d_in[5],
                           (const float*)d_in[8], (const float*)d_in[11]};
    const float* Wm[4]  = {(const float*)d_in[3], (const float*)d_in[6],
                           (const float*)d_in[9], (const float*)d_in[12]};
    const float* bm[4]  = {(const float*)d_in[4], (const float*)d_in[7],
                           (const float*)d_in[10], (const float*)d_in[13]};
    float* out = (float*)d_out;

    char* ws = (char*)d_ws;
    int* counts = (int*)ws;                        // 16 B
    int* lists = (int*)(ws + 16);                  // 4*32768*4 = 512 KB
    size_t off = (16 + (size_t)4 * TOKENS * 4 + 255) & ~(size_t)255;
    short* wt_arena = (short*)(ws + off);          // 1024*3328*2 = 6.8 MB
    off += (size_t)DOUT * 3328 * sizeof(short);
    off = (off + 255) & ~(size_t)255;
    short* a_arena = (short*)(ws + off);           // 32768*3328*2 = 218 MB
    off += (size_t)TOKENS * 3328 * sizeof(short);
    const bool fast = (ws_size >= off);

    hipMemsetAsync(counts, 0, 16, stream);
    compact_kernel<<<TOKENS / 256, 256, 0, stream>>>(token_ids, cat_table,
                                                     counts, lists);
    if (fast) {
        conv_w_kernel<<<dim3(104, 8), 256, 0, stream>>>(
            Wm[0], Wm[1], Wm[2], Wm[3], wt_arena);
        gather_a_kernel<<<dim3(128, 4), 256, 0, stream>>>(
            emb[0], emb[1], emb[2], emb[3], a_arena, lists, counts);
        // 33 chunks * 64 = 2112 blocks covers mt_total <= 260 with 8 nt each
        gemm_fused_kernel<<<2112, 256, 0, stream>>>(
            a_arena, wt_arena, bm[0], bm[1], bm[2], bm[3], lists, counts, out);
    } else {
        dim3 grid(TOKENS / 128, DOUT / 128);
        for (int c = 0; c < 4; ++c) {
            const int Ks[4] = {1536, 1024, 512, 256};
            gemm_direct_kernel<<<grid, 256, 0, stream>>>(
                emb[c], Wm[c], bm[c], lists + c * TOKENS, counts + c, out, Ks[c]);
        }
    }
}